// Round 4
// baseline (644.860 us; speedup 1.0000x reference)
//
#include <hip/hip_runtime.h>
#include <math.h>

// ResidualVQ fused forward, MI355X (gfx950) — round 8.
// R7 post-mortem: 435us main, all pipes <=30%. WRITE 161MB vs 68MB true ->
// out0 64B-stores at 512B stride cause L2 write-allocate RMW (also +67MB
// FETCH). ybuf round-trips + 224-thread GEMV + 6 barriers/layer serialize.
// R8: y RESIDENT in MFMA C-fragments for the whole kernel:
//  - GEMM accumulates into persistent acc[4] (+hv), no ybuf store
//  - per layer, owner wave drops the active 16-col chunk into ynow[32][20]
//  - corrections = 2 MFMA/chunk (A=-zq hi/lo, B=prebuilt Gf frags from L2)
//    accumulated straight into resident acc (GEMV/G32-staging/zqs deleted)
//  - out0/out1 deferred to one coalesced writer phase (no RMW amplification)
//  - conversions via v_cvt_pk_bf16_f32 (~3x fewer VALU)
//  - barriers 6->4 per layer, LDS 29KB->11KB
// fp64-recheck guard unchanged -> selection exactness preserved.

#define TAU 3e-4f

// ws byte offsets
#define WS_WACC   0
#define WS_HV64   64
#define WS_G64    2048
#define WS_CBN64  133120
#define WS_CBF    1247232   // 8192 codes x 32 ushort (bf16 hi|lo) = 512KB
#define WS_GF     1771520   // 64 pairs x 512 ushort B-frags = 64KB
#define WS_HV32   1837056
#define WS_BF     1837568   // B-fragments: hi 256KB | lo 256KB (pre-swizzled)
#define BF_LO_OFF 131072    // ushorts

typedef __attribute__((ext_vector_type(8))) short short8v;
typedef __attribute__((ext_vector_type(4))) float f32x4;
typedef __attribute__((ext_vector_type(4))) unsigned int uint4v;

__device__ __forceinline__ unsigned short bf16_rne(float x) {
    unsigned u = __float_as_uint(x);
    u += 0x7FFFu + ((u >> 16) & 1u);
    return (unsigned short)(u >> 16);
}
__device__ __forceinline__ float bf16_to_f32(unsigned short h) {
    return __uint_as_float(((unsigned)h) << 16);
}
__device__ __forceinline__ unsigned cvt_pk_bf16(float lo, float hi) {
    unsigned r;
    asm("v_cvt_pk_bf16_f32 %0, %1, %2" : "=v"(r) : "v"(lo), "v"(hi));
    return r;
}
// 8 floats -> bf16 hi frag + lo (residual) frag
__device__ __forceinline__ void cvt_hilo8(const float* v, short8v& hi, short8v& lo) {
    uint4v uh, ul;
#pragma unroll
    for (int i = 0; i < 4; ++i) {
        const unsigned u = cvt_pk_bf16(v[2 * i], v[2 * i + 1]);
        uh[i] = u;
        const float r0 = v[2 * i]     - __uint_as_float(u << 16);
        const float r1 = v[2 * i + 1] - __uint_as_float(u & 0xFFFF0000u);
        ul[i] = cvt_pk_bf16(r0, r1);
    }
    hi = __builtin_bit_cast(short8v, uh);
    lo = __builtin_bit_cast(short8v, ul);
}
__device__ __forceinline__ short8v vsel8(bool c, short8v a, short8v b) {
    uint4v ua = __builtin_bit_cast(uint4v, a);
    uint4v ub = __builtin_bit_cast(uint4v, b);
    uint4v r;
#pragma unroll
    for (int i = 0; i < 4; ++i) r[i] = c ? ua[i] : ub[i];
    return __builtin_bit_cast(short8v, r);
}

// ============================ prep (merged) ============================
// blocks: [0,32) cbn64+cbf | [32,96) Bf | [96,160) G64+Gf | [160,168) hv | 168 zero
__global__ void __launch_bounds__(256) rvq_prep(
    const float* __restrict__ cb, const float* __restrict__ Wd,
    const float* __restrict__ Wu, const float* __restrict__ bd,
    const float* __restrict__ bu,
    double* __restrict__ cbn64, unsigned short* __restrict__ cbf,
    unsigned short* __restrict__ Bf, unsigned short* __restrict__ Gf,
    double* __restrict__ G64,
    double* __restrict__ hv64, float* __restrict__ hv32,
    double* __restrict__ wacc)
{
    __shared__ double sm2[1200];
    float* smf = (float*)sm2;
    const int b = blockIdx.x, t = threadIdx.x;
    if (b < 32) {                       // normalized codebook fp64 + bf16 hi/lo
        const int idx = b * 256 + t;    // l*1024+k
        const float* cp = cb + (size_t)idx * 16;
        double v[16]; double n = 0.0;
#pragma unroll
        for (int c = 0; c < 16; ++c) { v[c] = (double)cp[c]; n = fma(v[c], v[c], n); }
        const double iv = 1.0 / fmax(sqrt(n), 1e-12);
        double* r64 = cbn64 + (size_t)idx * 17;
        unsigned short* cf = cbf + (size_t)idx * 32;
        double c2 = 0.0;
#pragma unroll
        for (int c = 0; c < 16; ++c) {
            const double x = v[c] * iv;
            c2 = fma(x, x, c2);
            r64[c] = x;
            const float xf = (float)x;
            const unsigned short hh = bf16_rne(xf);
            cf[c] = hh;
            cf[16 + c] = bf16_rne(xf - bf16_to_f32(hh));
        }
        r64[16] = c2;
    } else if (b < 96) {                // Bf: pre-swizzled bf16 hi/lo B-frags
        const int u = (b - 32) * 4 + (t >> 6);   // 0..255
        const int lane = t & 63;
        const int ks = u >> 3, ctg = u & 7;
        const int ic = ctg * 16 + (lane & 15);
        const int kb = ks * 32 + (lane >> 4) * 8;
        const float* wp = Wd + (size_t)ic * 1024 + kb;
        const float4 w0 = *(const float4*)wp;
        const float4 w1 = *(const float4*)(wp + 4);
        const float wv[8] = {w0.x, w0.y, w0.z, w0.w, w1.x, w1.y, w1.z, w1.w};
        unsigned short* dst = Bf + ((size_t)(ks * 8 + ctg) * 64 + lane) * 8;
#pragma unroll
        for (int i = 0; i < 8; ++i) {
            const unsigned short hh = bf16_rne(wv[i]);
            dst[i] = hh;
            dst[BF_LO_OFF + i] = bf16_rne(wv[i] - bf16_to_f32(hh));
        }
    } else if (b < 160) {               // G[j][i] = WuT_j . WdT_i (fp64) + Gf frags
        const int j = (b - 96) >> 3, i = (b - 96) & 7;
        if (j >= i) return;
        float* Aus = smf;               // [64][20] Wu[j, d, a]
        float* Bds = smf + 1280;        // [16][68] Wd[i, b, d]
        const int a = t >> 4, bb = t & 15;
        double s = 0.0;
        for (int ch = 0; ch < 16; ++ch) {
            __syncthreads();
            {
                const int dd = t >> 2, a4 = (t & 3) * 4;
                const float4 v = *(const float4*)(Wu + (size_t)j * 16384
                                  + (size_t)(ch * 64 + dd) * 16 + a4);
                *(float4*)&Aus[dd * 20 + a4] = v;
                const int br = t >> 4, d4 = (t & 15) * 4;
                const float4 w = *(const float4*)(Wd + (size_t)i * 16384
                                  + (size_t)br * 1024 + ch * 64 + d4);
                *(float4*)&Bds[br * 68 + d4] = w;
            }
            __syncthreads();
#pragma unroll
            for (int dd = 0; dd < 64; ++dd)
                s = fma((double)Aus[dd * 20 + a], (double)Bds[bb * 68 + dd], s);
        }
        G64[(size_t)(j * 8 + i) * 256 + t] = s;
        // Gf B-frag: B=[gh(k=a);gl(k=16+a)], element(k,col=bb):
        // lane=(k>>3)*16+col, i=k&7, pos=lane*8+i
        const float gs = (float)s;
        const unsigned short gh = bf16_rne(gs);
        const unsigned short gl = bf16_rne(gs - bf16_to_f32(gh));
        unsigned short* gf = Gf + (size_t)(j * 8 + i) * 512;
        gf[(((a >> 3) * 16 + bb) * 8) + (a & 7)] = gh;
        gf[((((a >> 3) + 2) * 16 + bb) * 8) + (a & 7)] = gl;
    } else if (b < 168) {               // hv row i (sbu computed inline)
        const int i = b - 160;
        const int dq = t >> 4, bb = t & 15;
        const float* wp = Wd + (size_t)i * 16384 + (size_t)bb * 1024 + dq * 64;
        const float* bup = bu + dq * 64;
        double s = 0.0;
        for (int dd = 0; dd < 64; ++dd) {
            double sb = 0.0;
            for (int j = 0; j < i; ++j) sb += (double)bup[j * 1024 + dd];
            s = fma(sb, (double)wp[dd], s);
        }
        sm2[dq * 20 + bb] = s;
        __syncthreads();
        if (t < 16) {
            double s2 = 0.0;
#pragma unroll
            for (int q = 0; q < 16; ++q) s2 += sm2[q * 20 + t];
            const double h = (double)bd[i * 16 + t] - s2;
            hv64[i * 16 + t] = h; hv32[i * 16 + t] = (float)h;
        }
    } else {
        if (t == 0) wacc[0] = 0.0;
    }
}

// ============================ main ============================
// 1024 blocks x 256 threads, 32 tokens/block, ~11KB LDS, 4 blocks/CU.
__global__ void __launch_bounds__(256, 4) rvq_main(
    const float* __restrict__ z_e, const float* __restrict__ Wd,
    const float* __restrict__ cb,
    const unsigned short* __restrict__ Bf, const float* __restrict__ hv32,
    const double* __restrict__ hv64,
    const unsigned short* __restrict__ cbf, const double* __restrict__ cbn64,
    const unsigned short* __restrict__ Gf, const double* __restrict__ G64,
    double* __restrict__ wacc,
    float* __restrict__ out0, float* __restrict__ out1)
{
    __shared__ __attribute__((aligned(16))) double stag_d[672]; // recheck scratch
    __shared__ float ynow[32 * 20];     // active 16-col y chunk
    __shared__ float candd[128], candd2[128];
    __shared__ int   candk[128];
    __shared__ int   bkhist[256];
    __shared__ int   bks[32], flist[32];
    __shared__ int   flagcnt;

    const int t = threadIdx.x;
    const int tok0g = blockIdx.x * 32;
    const int wq = t >> 6, lane = t & 63;
    const int blk = lane >> 4, col = lane & 15, kh = blk & 1;
    const bool lolane = blk >= 2;
    const int Tt = wq & 1, Ch = wq >> 1; // token-half / col-half of this wave

    // ---------------- GEMM into resident acc: y = z_e.WdT + hv ----------------
    f32x4 acc[4];
#pragma unroll
    for (int ct = 0; ct < 4; ++ct) acc[ct] = (f32x4){0.f, 0.f, 0.f, 0.f};
    {
        const float* zrow = z_e + (size_t)(tok0g + Tt * 16 + col) * 1024 + blk * 8;
        const unsigned short* bfh = Bf + ((size_t)(Ch * 4) * 64 + lane) * 8;
#pragma unroll 2
        for (int ks = 0; ks < 32; ++ks) {
            const float4 a0 = *(const float4*)(zrow + ks * 32);
            const float4 a1 = *(const float4*)(zrow + ks * 32 + 4);
            const float av[8] = {a0.x, a0.y, a0.z, a0.w, a1.x, a1.y, a1.z, a1.w};
            short8v ah, al;
            cvt_hilo8(av, ah, al);
            const unsigned short* bp = bfh + (size_t)ks * 4096;
#pragma unroll
            for (int ct = 0; ct < 4; ++ct) {
                const short8v bh = *(const short8v*)(bp + ct * 512);
                const short8v bl = *(const short8v*)(bp + BF_LO_OFF + ct * 512);
                acc[ct] = __builtin_amdgcn_mfma_f32_16x16x32_bf16(ah, bh, acc[ct], 0, 0, 0);
                acc[ct] = __builtin_amdgcn_mfma_f32_16x16x32_bf16(ah, bl, acc[ct], 0, 0, 0);
                acc[ct] = __builtin_amdgcn_mfma_f32_16x16x32_bf16(al, bh, acc[ct], 0, 0, 0);
            }
        }
#pragma unroll
        for (int ct = 0; ct < 4; ++ct) {
            const float hvv = hv32[Ch * 64 + ct * 16 + col];
#pragma unroll
            for (int r = 0; r < 4; ++r) acc[ct][r] += hvv;
        }
    }

    // ---------------- layer loop ----------------
    double lacc = 0.0;
#pragma unroll 1
    for (int l = 0; l < 8; ++l) {
        // owner wave drops the layer-l chunk (C-frag: row=blk*4+r, col)
        if (Ch == (l >> 2)) {
            const int ct = l & 3;
#pragma unroll
            for (int r = 0; r < 4; ++r)
                ynow[(Tt * 16 + blk * 4 + r) * 20 + col] = acc[ct][r];
        }
        __syncthreads();                // A: ynow ready

        // ---- normalize + A-frags (both token halves), in-register ----
        short8v af[2];
#pragma unroll
        for (int h = 0; h < 2; ++h) {
            const float* yp = &ynow[(h * 16 + col) * 20 + kh * 8];
            const float4 y0 = *(const float4*)yp;
            const float4 y1 = *(const float4*)(yp + 4);
            const float yv[8] = {y0.x, y0.y, y0.z, y0.w, y1.x, y1.y, y1.z, y1.w};
            float p = 0.f;
#pragma unroll
            for (int i = 0; i < 8; ++i) p = fmaf(yv[i], yv[i], p);
            const float n2 = p + __shfl_xor(p, 16);
            const float iv = 1.0f / fmaxf(sqrtf(n2), 1e-12f);
            float xv[8];
#pragma unroll
            for (int i = 0; i < 8; ++i) xv[i] = -2.f * (yv[i] * iv);
            short8v hi8, lo8;
            cvt_hilo8(xv, hi8, lo8);
            af[h] = vsel8(lolane, lo8, hi8);
        }

        // ---- distance scan: quarter wq, 16 tiles, both token halves ----
        float bs[2][4], bs2[2][4]; int bk[2][4];
#pragma unroll
        for (int h = 0; h < 2; ++h)
#pragma unroll
            for (int r = 0; r < 4; ++r) { bs[h][r] = 1e30f; bs2[h][r] = 1e30f; bk[h][r] = -1; }
        const unsigned short* cbp = cbf + ((size_t)(l * 1024 + wq * 256 + col)) * 32;
        const unsigned short* p1 = cbp + kh * 8;        // ch half
        const unsigned short* p2 = cbp + 16 + kh * 8;   // cl half (blk<2)
#pragma unroll 2
        for (int tile = 0; tile < 16; ++tile) {
            const short8v b1 = *(const short8v*)(p1 + tile * 512);
            short8v b2 = {};
            if (!lolane) b2 = *(const short8v*)(p2 + tile * 512);
            f32x4 aa[2];
            aa[0] = (f32x4){0.f, 0.f, 0.f, 0.f};
            aa[0] = __builtin_amdgcn_mfma_f32_16x16x32_bf16(af[0], b1, aa[0], 0, 0, 0);
            aa[0] = __builtin_amdgcn_mfma_f32_16x16x32_bf16(af[0], b2, aa[0], 0, 0, 0);
            aa[1] = (f32x4){0.f, 0.f, 0.f, 0.f};
            aa[1] = __builtin_amdgcn_mfma_f32_16x16x32_bf16(af[1], b1, aa[1], 0, 0, 0);
            aa[1] = __builtin_amdgcn_mfma_f32_16x16x32_bf16(af[1], b2, aa[1], 0, 0, 0);
            const int k = wq * 256 + tile * 16 + col;
#pragma unroll
            for (int h = 0; h < 2; ++h)
#pragma unroll
                for (int r = 0; r < 4; ++r) {
                    const float s = aa[h][r];
                    const bool wn = s < bs[h][r];
                    bs2[h][r] = wn ? bs[h][r] : fminf(bs2[h][r], s);
                    bk[h][r]  = wn ? k : bk[h][r];
                    bs[h][r]  = wn ? s : bs[h][r];
                }
        }

        // ---- lexicographic top-2 merge across the 16 cols ----
#pragma unroll
        for (int m = 1; m <= 8; m <<= 1)
#pragma unroll
            for (int h = 0; h < 2; ++h)
#pragma unroll
                for (int r = 0; r < 4; ++r) {
                    const float ob = __shfl_xor(bs[h][r], m);
                    const float os = __shfl_xor(bs2[h][r], m);
                    const int   ok = __shfl_xor(bk[h][r], m);
                    const bool wn = (ob < bs[h][r]) || (ob == bs[h][r] && ok < bk[h][r]);
                    const float loser = wn ? bs[h][r] : ob;
                    bs2[h][r] = fminf(fminf(bs2[h][r], os), loser);
                    bs[h][r]  = wn ? ob : bs[h][r];
                    bk[h][r]  = wn ? ok : bk[h][r];
                }
        if (t == 0) flagcnt = 0;
        if (col == 0) {                 // one writer lane per blk-group
#pragma unroll
            for (int h = 0; h < 2; ++h)
#pragma unroll
                for (int r = 0; r < 4; ++r) {
                    const int tok = h * 16 + blk * 4 + r;
                    candd [wq * 32 + tok] = bs[h][r];
                    candd2[wq * 32 + tok] = bs2[h][r];
                    candk [wq * 32 + tok] = bk[h][r];
                }
        }
        __syncthreads();                // B: candidates ready
        if (t < 32) {                   // final merge over 4 quarters + flag
            float best = 1e30f, sec = 1e30f; int bkk = -1;
#pragma unroll
            for (int c = 0; c < 4; ++c) {
                const float d  = candd [c * 32 + t];
                const float d2 = candd2[c * 32 + t];
                const int   k  = candk [c * 32 + t];
                const bool wn = (d < best) || (d == best && k < bkk);
                const float nw = fminf(sec, fminf(best, d2));
                const float nl = fminf(sec, d);
                sec  = wn ? nw : nl;
                bkk  = wn ? k : bkk;
                best = wn ? d : best;
            }
            bks[t] = bkk;
            float n2 = 0.f;
#pragma unroll
            for (int c = 0; c < 16; ++c) {
                const float yv = ynow[t * 20 + c];
                n2 = fmaf(yv, yv, n2);
            }
            if ((sec - best < TAU) || (n2 < 1e-3f)) {
                const int p = atomicAdd(&flagcnt, 1); flist[p] = t;
            }
        }
        __syncthreads();                // C: bks/flags ready

        // ---- rare fp64 recheck (exact reference argmin) ----
        const int nf = flagcnt;
#pragma unroll 1
        for (int f = 0; f < nf; ++f) {
            const int tok = flist[f];
            double* rpd = stag_d;
            {
                const int c = t & 15, ch = t >> 4;
                const float* gz = z_e + (size_t)(tok0g + tok) * 1024 + ch * 64;
                const float* wp = Wd + ((size_t)l * 16 + c) * 1024 + ch * 64;
                double pd = 0.0;
                for (int dd = 0; dd < 64; ++dd)
                    pd = fma((double)gz[dd], (double)wp[dd], pd);
                rpd[c * 16 + ch] = pd;
            }
            __syncthreads();
            if (t < 16) {
                double y = hv64[l * 16 + t];
#pragma unroll
                for (int ch = 0; ch < 16; ++ch) y += rpd[t * 16 + ch];
                for (int j = 0; j < l; ++j) {
                    const int bkj = bkhist[tok * 8 + j];
                    const float* qv = cb + ((size_t)j * 1024 + bkj) * 16;
                    const double* gp = G64 + (size_t)(j * 8 + l) * 256 + t;
                    double s = 0.0;
#pragma unroll
                    for (int a = 0; a < 16; ++a)
                        s = fma((double)qv[a], gp[a * 16], s);
                    y -= s;
                }
                rpd[256 + t] = y;
            }
            __syncthreads();
            if (t == 0) {
                double n2 = 0.0;
#pragma unroll
                for (int c = 0; c < 16; ++c) n2 = fma(rpd[256 + c], rpd[256 + c], n2);
                const double iv = 1.0 / fmax(sqrt(n2), 1e-12);
#pragma unroll
                for (int c = 0; c < 16; ++c) rpd[272 + c] = rpd[256 + c] * iv;
            }
            __syncthreads();
            {
                double bd_ = 1e300; int bk_ = -1;
#pragma unroll
                for (int qq = 0; qq < 4; ++qq) {
                    const int k = qq * 256 + t;
                    const double* row = cbn64 + (size_t)(l * 1024 + k) * 17;
                    double dot = 0.0;
#pragma unroll
                    for (int c = 0; c < 16; ++c) dot = fma(row[c], rpd[272 + c], dot);
                    const double s = fma(-2.0, dot, row[16]);
                    if (s < bd_) { bd_ = s; bk_ = k; }
                }
                rpd[288 + t] = bd_;
                ((int*)&rpd[544])[t] = bk_;
            }
            __syncthreads();
            if (t == 0) {
                double bd_ = 1e300; int bk_ = -1;
                for (int i = 0; i < 256; ++i) {
                    const double d = rpd[288 + i];
                    const int k = ((int*)&rpd[544])[i];
                    if (d < bd_ || (d == bd_ && k < bk_)) { bd_ = d; bk_ = k; }
                }
                bks[tok] = bk_;
            }
            __syncthreads();
        }

        // ---- bookkeeping + loss (t<32) ----
        if (t < 32) {
            const int bk_ = bks[t];
            bkhist[t * 8 + l] = bk_;
            const float4* qp = (const float4*)(cb + ((size_t)l * 1024 + bk_) * 16);
            const float4 q0 = qp[0], q1 = qp[1], q2 = qp[2], q3 = qp[3];
            const float qf[16] = {q0.x,q0.y,q0.z,q0.w, q1.x,q1.y,q1.z,q1.w,
                                  q2.x,q2.y,q2.z,q2.w, q3.x,q3.y,q3.z,q3.w};
#pragma unroll
            for (int c = 0; c < 16; ++c) {
                const float d = ynow[t * 20 + c] - qf[c];
                lacc += (double)d * (double)d;
            }
        }

        // ---- corrections: acc[ct] -= zq.G[l][ii] via 2 MFMA per future chunk ----
        if (l < 7) {
            const int code = bks[Tt * 16 + col];
            const float* qrow = cb + ((size_t)l * 1024 + code) * 16 + kh * 8;
            const float4 q0 = *(const float4*)qrow;
            const float4 q1 = *(const float4*)(qrow + 4);
            const float xv[8] = {-q0.x, -q0.y, -q0.z, -q0.w,
                                 -q1.x, -q1.y, -q1.z, -q1.w};
            short8v zh8, zl8;
            cvt_hilo8(xv, zh8, zl8);
            const short8v zero = {};
            const short8v a1 = zh8;                    // [zh|zh]
            const short8v a2 = vsel8(lolane, zero, zl8); // [zl|0]
#pragma unroll
            for (int ct = 0; ct < 4; ++ct) {
                const int ii = Ch * 4 + ct;
                if (ii > l) {
                    const short8v b1 = *(const short8v*)(Gf +
                        ((size_t)(l * 8 + ii)) * 512 + lane * 8);  // [gh;gl]
                    const short8v b2 = vsel8(lolane, zero, b1);    // [gh;0]
                    acc[ct] = __builtin_amdgcn_mfma_f32_16x16x32_bf16(a1, b1, acc[ct], 0, 0, 0);
                    acc[ct] = __builtin_amdgcn_mfma_f32_16x16x32_bf16(a2, b2, acc[ct], 0, 0, 0);
                }
            }
        }
        __syncthreads();                // D: ynow/loss reads done before rewrite
    }

    // ---------------- deferred coalesced outputs ----------------
    {
        const int tok = t >> 3, li = t & 7;
        const int code = bkhist[tok * 8 + li];
        const float4* qp = (const float4*)(cb + ((size_t)li * 1024 + code) * 16);
        float* op = out0 + (size_t)(tok0g + tok) * 128 + li * 16;
        ((float4*)op)[0] = qp[0]; ((float4*)op)[1] = qp[1];
        ((float4*)op)[2] = qp[2]; ((float4*)op)[3] = qp[3];
        out1[(size_t)(tok0g + tok) * 8 + li] = (float)code;
    }

    if (t < 64) {
#pragma unroll
        for (int off = 32; off > 0; off >>= 1) lacc += __shfl_down(lacc, off);
        if (t == 0) atomicAdd(wacc, lacc);
    }
}

__global__ void __launch_bounds__(64) rvq_fin(const double* __restrict__ wacc,
                                              float* __restrict__ lossp) {
    if (threadIdx.x == 0) {
        const float v = (float)(wacc[0] * (1.0 / 524288.0));
        lossp[0] = v; lossp[1] = v; lossp[2] = 0.0f;
    }
}

extern "C" void kernel_launch(void* const* d_in, const int* in_sizes, int n_in,
                              void* d_out, int out_size, void* d_ws, size_t ws_size,
                              hipStream_t stream) {
    (void)in_sizes; (void)n_in; (void)ws_size;
    const float* z_e = (const float*)d_in[0];
    const float* Wd  = (const float*)d_in[1];
    const float* bd  = (const float*)d_in[2];
    const float* cb  = (const float*)d_in[3];
    const float* Wu  = (const float*)d_in[4];
    const float* bu  = (const float*)d_in[5];

    float* out0  = (float*)d_out;                      // (8,4096,128)
    float* out1  = out0 + (size_t)8 * 4096 * 128;      // (8,4096,8) codes
    float* lossp = out0 + (size_t)out_size - 3;        // commit, cbl, entropy

    char* ws = (char*)d_ws;
    double* wacc  = (double*)(ws + WS_WACC);
    double* hv64  = (double*)(ws + WS_HV64);
    double* G64   = (double*)(ws + WS_G64);
    double* cbn64 = (double*)(ws + WS_CBN64);
    unsigned short* cbf = (unsigned short*)(ws + WS_CBF);
    unsigned short* Gf  = (unsigned short*)(ws + WS_GF);
    float*  hv32  = (float*) (ws + WS_HV32);
    unsigned short* Bf  = (unsigned short*)(ws + WS_BF);

    rvq_prep<<<169, 256, 0, stream>>>(cb, Wd, Wu, bd, bu, cbn64, cbf, Bf, Gf,
                                      G64, hv64, hv32, wacc);
    rvq_main<<<1024, 256, 0, stream>>>(z_e, Wd, cb, Bf, hv32, hv64,
                                       cbf, cbn64, Gf, G64, wacc, out0, out1);
    rvq_fin<<<1, 64, 0, stream>>>(wacc, lossp);
}